// Round 6
// baseline (252.456 us; speedup 1.0000x reference)
//
#include <hip/hip_runtime.h>
#include <math.h>

#define B    1024
#define NI   32
#define NH   1024

// ws layout (floats), degree-sorted hidden index "s":
//   W1t [32][1024]  : W1t[j][s] = m1-masked W1[orig(s)][j]
//   b1s [1088]      : sorted b1 + 64 zero pad (phase-A lane overread)
//   b2s [1024]
//   W2t [1024][1024]: W2t[sh][sg] = m2-masked W2[orig(sg)][orig(sh)]
//   W3s [64][1024]  : m3-masked, sorted columns
#define OFF_W1T 0
#define OFF_B1S (NI * NH)              // 32768
#define OFF_B2S (OFF_B1S + NH + 64)    // 33856
#define OFF_W2T (OFF_B2S + NH)         // 34880
#define OFF_W3S (OFF_W2T + NH * NH)    // 1083456
// total = 1148992 floats (~4.6 MB). Phase-B zero-weighted u>=cnt overreads of
// up to ~3 rows past W2T land inside W3S (finite, multiplied by 0.0).

// orig h -> (deg, sorted idx). deg0 has 34 units (h=31k), deg d>=1 has 33.
__device__ __forceinline__ int sidx_of(int h, int& d) {
    d = h % 31;
    int k = h / 31;
    return (d == 0) ? k : (33 * d + 1 + k);
}

// One prep launch. blockIdx: [0,256) W2 64x64 tiled transpose (coalesced 4MB
// read, LDS transpose, scattered 4B writes absorbed by L2); [256,320) W3 rows;
// [320,352) W1t rows; 352 biases.
__global__ __launch_bounds__(256) void prep_all(
        const float* __restrict__ W1, const float* __restrict__ b1,
        const float* __restrict__ W2, const float* __restrict__ b2,
        const float* __restrict__ W3, float* __restrict__ ws) {
    const int bid = blockIdx.x, t = threadIdx.x;
    if (bid < 256) {                                    // W2 tile (T0=og, T1=oh)
        __shared__ float tile[64][65];
        const int T0 = (bid >> 4) * 64, T1 = (bid & 15) * 64;
#pragma unroll
        for (int it = 0; it < 4; ++it) {                // coalesced float4 reads
            int r = it * 16 + (t >> 4);
            int c = (t & 15) * 4;
            float4 v = *(const float4*)(W2 + (size_t)(T0 + r) * NH + T1 + c);
            tile[r][c] = v.x; tile[r][c + 1] = v.y;
            tile[r][c + 2] = v.z; tile[r][c + 3] = v.w;
        }
        __syncthreads();
        const int c = t >> 2;                           // oh index in tile
        int dh; const int sh = sidx_of(T1 + c, dh);
        float* orow = ws + OFF_W2T + (size_t)sh * NH;
#pragma unroll
        for (int k = 0; k < 16; ++k) {
            int ogl = (t & 3) * 16 + k;
            int dg; int sg = sidx_of(T0 + ogl, dg);
            orow[sg] = (dg >= dh) ? tile[ogl][c] : 0.0f;
        }
    } else if (bid < 320) {                             // W3s row o
        const int o = bid - 256, od = (o & 31) - 1;
        float4 v = *(const float4*)(W3 + (size_t)o * NH + 4 * t);
        float vv[4] = {v.x, v.y, v.z, v.w};
#pragma unroll
        for (int cc = 0; cc < 4; ++cc) {
            int d; int s = sidx_of(4 * t + cc, d);
            ws[OFF_W3S + (size_t)o * NH + s] = (od >= d) ? vv[cc] : 0.0f;
        }
    } else if (bid < 352) {                             // W1t row j
        const int j = bid - 320;
#pragma unroll
        for (int cc = 0; cc < 4; ++cc) {
            int h = 4 * t + cc;
            int d; int s = sidx_of(h, d);
            ws[OFF_W1T + (size_t)j * NH + s] = (d >= j) ? W1[h * NI + j] : 0.0f;
        }
    } else {                                            // biases + pad
#pragma unroll
        for (int cc = 0; cc < 4; ++cc) {
            int h = 4 * t + cc;
            int d; int s = sidx_of(h, d);
            ws[OFF_B1S + s] = b1[h];
            ws[OFF_B2S + s] = b2[h];
        }
        if (t < 16) ((float4*)(ws + OFF_B1S + NH))[t] = make_float4(0, 0, 0, 0);
    }
}

// Block = 4 batch rows x 8 slice-waves (width 128, float2/lane). 256 blocks x
// 512 thr = 2048 waves = 2 waves/SIMD, while keeping 4x row reuse per W2t load
// (8 FMA / 8B). Panel addresses are static: first 12 float2 prefetched before
// the data-dependent phase-A chain. One barrier/step.
__global__ __launch_bounds__(512, 2) void made_scan(
        const float* __restrict__ inputs,
        const float* __restrict__ b3,
        const float* __restrict__ ws,
        float* __restrict__ out) {
    __shared__ float part[2][8][8];      // [buf][wave][s00,s01,s10,s11,s20,s21,s30,s31]

    const int lane = threadIdx.x & 63;
    const int w    = threadIdx.x >> 6;   // 0..7
    const int gb   = w * 128;            // slice base; g = gb + 2*lane + {0,1}
    const int row0 = blockIdx.x * 4;

    const float* W1t = ws + OFF_W1T;
    const float* b1s = ws + OFF_B1S;
    const float* b2s = ws + OFF_B2S;
    const float* W2t = ws + OFF_W2T;
    const float* W3s = ws + OFF_W3S;

    float2 acc0, acc1, acc2, acc3;
    acc0 = acc1 = acc2 = acc3 = ((const float2*)(b2s + gb))[lane];

    float xin0 = (lane < NI) ? inputs[(row0 + 0) * NI + lane] : 0.0f;
    float xin1 = (lane < NI) ? inputs[(row0 + 1) * NI + lane] : 0.0f;
    float xin2 = (lane < NI) ? inputs[(row0 + 2) * NI + lane] : 0.0f;
    float xin3 = (lane < NI) ? inputs[(row0 + 3) * NI + lane] : 0.0f;
    float b3v = b3[lane];
    float xr0 = 0, xr1 = 0, xr2 = 0, xr3 = 0;   // x_j lives in lane j, per row
    float J0 = 0, J1 = 0, J2 = 0, J3 = 0;

    for (int i = 0; i < NI; ++i) {
        const int goff = (i <= 1) ? 0 : (33 * (i - 1) + 1);
        const int cnt  = (i == 0) ? 0 : ((i == 1) ? 34 : 33);
        const int L    = (i == 0) ? 0 : (33 * i + 1);
        const bool doB = (i > 0) && (gb + 128 > goff);
        const bool doC = (gb < L);

        // phase-C weights prefetch (static addresses)
        float2 wa = make_float2(0, 0), wb = make_float2(0, 0);
        if (doC) {
            wa = ((const float2*)(W3s + (size_t)i * NH + gb))[lane];
            wb = ((const float2*)(W3s + (size_t)(NI + i) * NH + gb))[lane];
        }

        if (doB) {
            const float* rb = W2t + (size_t)goff * NH + gb;
            // prefetch first 12 panel rows (independent of phase A)
            float2 P[12];
#pragma unroll
            for (int u = 0; u < 12; ++u)
                P[u] = ((const float2*)(rb + (size_t)u * NH))[lane];

            // ---- Phase A: a1 for the cnt units finalized this step, 4 rows.
            const int su = goff + lane;
            float bz = b1s[su];
            float z0 = bz, z1 = bz, z2 = bz, z3 = bz;
            const int jmax = (i + 3) & ~3;
            for (int j = 0; j < jmax; j += 4) {
#pragma unroll
                for (int jj = 0; jj < 4; ++jj) {
                    float w1v = W1t[(j + jj) * NH + su];
                    z0 = fmaf(__shfl(xr0, j + jj, 64), w1v, z0);
                    z1 = fmaf(__shfl(xr1, j + jj, 64), w1v, z1);
                    z2 = fmaf(__shfl(xr2, j + jj, 64), w1v, z2);
                    z3 = fmaf(__shfl(xr3, j + jj, 64), w1v, z3);
                }
            }
            const bool ok = lane < cnt;
            float a10 = ok ? fmaxf(z0, 0.0f) : 0.0f;
            float a11 = ok ? fmaxf(z1, 0.0f) : 0.0f;
            float a12 = ok ? fmaxf(z2, 0.0f) : 0.0f;
            float a13 = ok ? fmaxf(z3, 0.0f) : 0.0f;

            // ---- Phase B: prefetched head
#pragma unroll
            for (int u = 0; u < 12; ++u) {
                float2 wv = P[u];
                float c0 = __shfl(a10, u, 64), c1 = __shfl(a11, u, 64);
                float c2 = __shfl(a12, u, 64), c3 = __shfl(a13, u, 64);
                acc0.x = fmaf(c0, wv.x, acc0.x); acc0.y = fmaf(c0, wv.y, acc0.y);
                acc1.x = fmaf(c1, wv.x, acc1.x); acc1.y = fmaf(c1, wv.y, acc1.y);
                acc2.x = fmaf(c2, wv.x, acc2.x); acc2.y = fmaf(c2, wv.y, acc2.y);
                acc3.x = fmaf(c3, wv.x, acc3.x); acc3.y = fmaf(c3, wv.y, acc3.y);
            }
            // ---- Phase B: streamed tail (loads overlap head FMAs)
#pragma unroll
            for (int u = 12; u < 36; ++u) {
                float2 wv = ((const float2*)(rb + (size_t)u * NH))[lane];
                float c0 = __shfl(a10, u, 64), c1 = __shfl(a11, u, 64);
                float c2 = __shfl(a12, u, 64), c3 = __shfl(a13, u, 64);
                acc0.x = fmaf(c0, wv.x, acc0.x); acc0.y = fmaf(c0, wv.y, acc0.y);
                acc1.x = fmaf(c1, wv.x, acc1.x); acc1.y = fmaf(c1, wv.y, acc1.y);
                acc2.x = fmaf(c2, wv.x, acc2.x); acc2.y = fmaf(c2, wv.y, acc2.y);
                acc3.x = fmaf(c3, wv.x, acc3.x); acc3.y = fmaf(c3, wv.y, acc3.y);
            }
        }

        // ---- Phase C: slice partials (W3s zeros beyond prefix L)
        float s00 = 0, s01 = 0, s10 = 0, s11 = 0;
        float s20 = 0, s21 = 0, s30 = 0, s31 = 0;
        if (doC) {
            float h0, h1;
            h0 = fmaxf(acc0.x, 0.0f); h1 = fmaxf(acc0.y, 0.0f);
            s00 = fmaf(wa.x, h0, wa.y * h1); s01 = fmaf(wb.x, h0, wb.y * h1);
            h0 = fmaxf(acc1.x, 0.0f); h1 = fmaxf(acc1.y, 0.0f);
            s10 = fmaf(wa.x, h0, wa.y * h1); s11 = fmaf(wb.x, h0, wb.y * h1);
            h0 = fmaxf(acc2.x, 0.0f); h1 = fmaxf(acc2.y, 0.0f);
            s20 = fmaf(wa.x, h0, wa.y * h1); s21 = fmaf(wb.x, h0, wb.y * h1);
            h0 = fmaxf(acc3.x, 0.0f); h1 = fmaxf(acc3.y, 0.0f);
            s30 = fmaf(wa.x, h0, wa.y * h1); s31 = fmaf(wb.x, h0, wb.y * h1);
        }
#pragma unroll
        for (int m = 32; m >= 1; m >>= 1) {
            s00 += __shfl_xor(s00, m, 64); s01 += __shfl_xor(s01, m, 64);
            s10 += __shfl_xor(s10, m, 64); s11 += __shfl_xor(s11, m, 64);
            s20 += __shfl_xor(s20, m, 64); s21 += __shfl_xor(s21, m, 64);
            s30 += __shfl_xor(s30, m, 64); s31 += __shfl_xor(s31, m, 64);
        }
        if (lane == 0) {
            float* pp = &part[i & 1][w][0];
            ((float4*)pp)[0] = make_float4(s00, s01, s10, s11);
            ((float4*)pp)[1] = make_float4(s20, s21, s30, s31);
        }
        __syncthreads();

        // combine 8 waves' partials (LDS broadcast reads), rows packed in lane&3
        const float* pb = &part[i & 1][0][0];
        float4 Aq = make_float4(0, 0, 0, 0), Bq = make_float4(0, 0, 0, 0);
#pragma unroll
        for (int ww = 0; ww < 8; ++ww) {
            float4 ta = ((const float4*)pb)[2 * ww];
            float4 tb = ((const float4*)pb)[2 * ww + 1];
            Aq.x += ta.x; Aq.y += ta.y; Aq.z += ta.z; Aq.w += ta.w;
            Bq.x += tb.x; Bq.y += tb.y; Bq.z += tb.z; Bq.w += tb.w;
        }
        const int lr = lane & 3;
        float p0p = (lr == 0) ? Aq.x : (lr == 1) ? Aq.z : (lr == 2) ? Bq.x : Bq.z;
        float p1p = (lr == 0) ? Aq.y : (lr == 1) ? Aq.w : (lr == 2) ? Bq.y : Bq.w;
        p0p += __shfl(b3v, i, 64);
        p1p += __shfl(b3v, NI + i, 64);
        float xi0 = __shfl(xin0, i, 64), xi1 = __shfl(xin1, i, 64);
        float xi2 = __shfl(xin2, i, 64), xi3 = __shfl(xin3, i, 64);
        float xinp = (lr == 0) ? xi0 : (lr == 1) ? xi1 : (lr == 2) ? xi2 : xi3;
        float e2 = __expf(2.0f * fminf(p1p, 15.0f));   // tanh; exact sat both ends
        float ap = (e2 - 1.0f) / (e2 + 1.0f);
        float xp = fmaf(xinp, __expf(ap), p0p);
        float av0 = __shfl(ap, 0, 64), av1 = __shfl(ap, 1, 64);
        float av2 = __shfl(ap, 2, 64), av3 = __shfl(ap, 3, 64);
        float xv0 = __shfl(xp, 0, 64), xv1 = __shfl(xp, 1, 64);
        float xv2 = __shfl(xp, 2, 64), xv3 = __shfl(xp, 3, 64);
        J0 -= av0; J1 -= av1; J2 -= av2; J3 -= av3;
        if (lane == i) { xr0 = xv0; xr1 = xv1; xr2 = xv2; xr3 = xv3; }
    }

    if (w == 0) {
        if (lane < NI) {
            out[(row0 + 0) * NI + lane] = xr0;
            out[(row0 + 1) * NI + lane] = xr1;
            out[(row0 + 2) * NI + lane] = xr2;
            out[(row0 + 3) * NI + lane] = xr3;
        }
        if (lane < 4) {
            float Jv = (lane == 0) ? J0 : (lane == 1) ? J1 : (lane == 2) ? J2 : J3;
            out[B * NI + row0 + lane] = Jv;
        }
    }
}

extern "C" void kernel_launch(void* const* d_in, const int* in_sizes, int n_in,
                              void* d_out, int out_size, void* d_ws, size_t ws_size,
                              hipStream_t stream) {
    const float* inputs = (const float*)d_in[0];
    const float* W1     = (const float*)d_in[1];
    const float* b1     = (const float*)d_in[2];
    const float* W2     = (const float*)d_in[3];
    const float* b2     = (const float*)d_in[4];
    const float* W3     = (const float*)d_in[5];
    const float* b3     = (const float*)d_in[6];
    float* out = (float*)d_out;
    float* ws  = (float*)d_ws;

    prep_all<<<353, 256, 0, stream>>>(W1, b1, W2, b2, W3, ws);
    made_scan<<<B / 4, 512, 0, stream>>>(inputs, b3, ws, out);
}

// Round 7
// 231.554 us; speedup vs baseline: 1.0903x; 1.0903x over previous
//
#include <hip/hip_runtime.h>
#include <math.h>

#define B    1024
#define NI   32
#define NH   1024

// ws layout (floats), degree-sorted hidden index "s":
//   W1t [32][1024]  : W1t[j][s] = m1-masked W1[orig(s)][j]
//   b1s [1088]      : sorted b1 + 64 zero pad (phase-A lane overread)
//   b2s [1024]
//   W2t [1024][1024]: W2t[sh][sg] = m2-masked W2[orig(sg)][orig(sh)]
//   W3s [64][1024]  : m3-masked, sorted columns
#define OFF_W1T 0
#define OFF_B1S (NI * NH)              // 32768
#define OFF_B2S (OFF_B1S + NH + 64)    // 33856
#define OFF_W2T (OFF_B2S + NH)         // 34880
#define OFF_W3S (OFF_W2T + NH * NH)    // 1083456
// total = 1148992 floats (~4.6 MB). Phase-B zero-weighted u>=cnt overreads of
// up to ~3 rows past W2T land inside W3S (finite, multiplied by 0.0).

// orig h -> (deg, sorted idx). deg0 has 34 units (h=31k), deg d>=1 has 33.
__device__ __forceinline__ int sidx_of(int h, int& d) {
    d = h % 31;
    int k = h / 31;
    return (d == 0) ? k : (33 * d + 1 + k);
}

// One prep launch. blockIdx: [0,256) W2 64x64 tiled transpose (coalesced 4MB
// read, LDS transpose, scattered 4B writes absorbed by L2); [256,320) W3 rows;
// [320,352) W1t rows; 352 biases.
__global__ __launch_bounds__(256) void prep_all(
        const float* __restrict__ W1, const float* __restrict__ b1,
        const float* __restrict__ W2, const float* __restrict__ b2,
        const float* __restrict__ W3, float* __restrict__ ws) {
    const int bid = blockIdx.x, t = threadIdx.x;
    if (bid < 256) {                                    // W2 tile (T0=og, T1=oh)
        __shared__ float tile[64][65];
        const int T0 = (bid >> 4) * 64, T1 = (bid & 15) * 64;
#pragma unroll
        for (int it = 0; it < 4; ++it) {                // coalesced float4 reads
            int r = it * 16 + (t >> 4);
            int c = (t & 15) * 4;
            float4 v = *(const float4*)(W2 + (size_t)(T0 + r) * NH + T1 + c);
            tile[r][c] = v.x; tile[r][c + 1] = v.y;
            tile[r][c + 2] = v.z; tile[r][c + 3] = v.w;
        }
        __syncthreads();
        const int c = t >> 2;                           // oh index in tile
        int dh; const int sh = sidx_of(T1 + c, dh);
        float* orow = ws + OFF_W2T + (size_t)sh * NH;
#pragma unroll
        for (int k = 0; k < 16; ++k) {
            int ogl = (t & 3) * 16 + k;
            int dg; int sg = sidx_of(T0 + ogl, dg);
            orow[sg] = (dg >= dh) ? tile[ogl][c] : 0.0f;
        }
    } else if (bid < 320) {                             // W3s row o
        const int o = bid - 256, od = (o & 31) - 1;
        float4 v = *(const float4*)(W3 + (size_t)o * NH + 4 * t);
        float vv[4] = {v.x, v.y, v.z, v.w};
#pragma unroll
        for (int cc = 0; cc < 4; ++cc) {
            int d; int s = sidx_of(4 * t + cc, d);
            ws[OFF_W3S + (size_t)o * NH + s] = (od >= d) ? vv[cc] : 0.0f;
        }
    } else if (bid < 352) {                             // W1t row j
        const int j = bid - 320;
#pragma unroll
        for (int cc = 0; cc < 4; ++cc) {
            int h = 4 * t + cc;
            int d; int s = sidx_of(h, d);
            ws[OFF_W1T + (size_t)j * NH + s] = (d >= j) ? W1[h * NI + j] : 0.0f;
        }
    } else {                                            // biases + pad
#pragma unroll
        for (int cc = 0; cc < 4; ++cc) {
            int h = 4 * t + cc;
            int d; int s = sidx_of(h, d);
            ws[OFF_B1S + s] = b1[h];
            ws[OFF_B2S + s] = b2[h];
        }
        if (t < 16) ((float4*)(ws + OFF_B1S + NH))[t] = make_float4(0, 0, 0, 0);
    }
}

__device__ __forceinline__ void rank1(float4 wv, float c0, float c1, float c2,
                                      float c3, float4& a0, float4& a1,
                                      float4& a2, float4& a3) {
    a0.x = fmaf(c0, wv.x, a0.x); a0.y = fmaf(c0, wv.y, a0.y);
    a0.z = fmaf(c0, wv.z, a0.z); a0.w = fmaf(c0, wv.w, a0.w);
    a1.x = fmaf(c1, wv.x, a1.x); a1.y = fmaf(c1, wv.y, a1.y);
    a1.z = fmaf(c1, wv.z, a1.z); a1.w = fmaf(c1, wv.w, a1.w);
    a2.x = fmaf(c2, wv.x, a2.x); a2.y = fmaf(c2, wv.y, a2.y);
    a2.z = fmaf(c2, wv.z, a2.z); a2.w = fmaf(c2, wv.w, a2.w);
    a3.x = fmaf(c3, wv.x, a3.x); a3.y = fmaf(c3, wv.y, a3.y);
    a3.z = fmaf(c3, wv.z, a3.z); a3.w = fmaf(c3, wv.w, a3.w);
}

// Block = 4 batch rows x 4 slice-waves (float4/lane), 256 blocks = 1/CU.
// Deep software pipeline: step i+1's panel head (12 rows) + W3 rows prefetched
// into registers BEFORE the barrier; tail (24 rows) issued in two register
// groups at step start; phase A is a fixed fully-unrolled 32-tap (all W1t
// loads hoisted). One barrier/step.
__global__ __launch_bounds__(256, 1) void made_scan(
        const float* __restrict__ inputs,
        const float* __restrict__ b3,
        const float* __restrict__ ws,
        float* __restrict__ out) {
    __shared__ float part[2][4][8];      // [buf][wave][s00,s01,s10,s11,s20,s21,s30,s31]

    const int lane = threadIdx.x & 63;
    const int w    = threadIdx.x >> 6;   // 0..3
    const int gb   = w * 256;            // slice base; g = gb + 4*lane + c
    const int row0 = blockIdx.x * 4;

    const float* W1t = ws + OFF_W1T;
    const float* b1s = ws + OFF_B1S;
    const float* b2s = ws + OFF_B2S;
    const float* W2t = ws + OFF_W2T;
    const float* W3s = ws + OFF_W3S;

    float4 acc0, acc1, acc2, acc3;       // z2 slice per row
    acc0 = acc1 = acc2 = acc3 = ((const float4*)(b2s + gb))[lane];

    float xin0 = (lane < NI) ? inputs[(row0 + 0) * NI + lane] : 0.0f;
    float xin1 = (lane < NI) ? inputs[(row0 + 1) * NI + lane] : 0.0f;
    float xin2 = (lane < NI) ? inputs[(row0 + 2) * NI + lane] : 0.0f;
    float xin3 = (lane < NI) ? inputs[(row0 + 3) * NI + lane] : 0.0f;
    float b3v = b3[lane];
    float xr0 = 0, xr1 = 0, xr2 = 0, xr3 = 0;   // x_j lives in lane j, per row
    float J0 = 0, J1 = 0, J2 = 0, J3 = 0;

    float4 P[12];                        // cross-barrier panel head prefetch
    float4 wa = make_float4(0, 0, 0, 0), wb = make_float4(0, 0, 0, 0);

    for (int i = 0; i < NI; ++i) {
        const int goff = (i <= 1) ? 0 : (33 * (i - 1) + 1);
        const int cnt  = (i == 0) ? 0 : ((i == 1) ? 34 : 33);
        const int L    = (i == 0) ? 0 : (33 * i + 1);
        const bool doB = (i > 0) && (gb + 256 > goff);
        const bool doC = (gb < L);

        if (doB) {
            const float* rb = W2t + (size_t)goff * NH + gb;
            float4 M[12], T[12];
            // issue mid group immediately (independent of phase A)
#pragma unroll
            for (int u = 0; u < 12; ++u)
                M[u] = ((const float4*)(rb + (size_t)(12 + u) * NH))[lane];

            // ---- Phase A: fixed 32 taps, fully unrolled -> all loads hoisted.
            // Taps j >= i are exact zeros (masked W1t / xr = 0).
            const int su = goff + lane;
            float bz = b1s[su];
            float z0 = bz, z1 = bz, z2v = bz, z3v = bz;
#pragma unroll
            for (int j = 0; j < 32; ++j) {
                float w1v = W1t[j * NH + su];
                z0  = fmaf(__shfl(xr0, j, 64), w1v, z0);
                z1  = fmaf(__shfl(xr1, j, 64), w1v, z1);
                z2v = fmaf(__shfl(xr2, j, 64), w1v, z2v);
                z3v = fmaf(__shfl(xr3, j, 64), w1v, z3v);
            }
            const bool ok = lane < cnt;
            float a10 = ok ? fmaxf(z0, 0.0f) : 0.0f;
            float a11 = ok ? fmaxf(z1, 0.0f) : 0.0f;
            float a12 = ok ? fmaxf(z2v, 0.0f) : 0.0f;
            float a13 = ok ? fmaxf(z3v, 0.0f) : 0.0f;

            // issue tail group, then consume head (already resident), mid, tail
#pragma unroll
            for (int u = 0; u < 12; ++u)
                T[u] = ((const float4*)(rb + (size_t)(24 + u) * NH))[lane];
#pragma unroll
            for (int u = 0; u < 12; ++u)
                rank1(P[u], __shfl(a10, u, 64), __shfl(a11, u, 64),
                      __shfl(a12, u, 64), __shfl(a13, u, 64),
                      acc0, acc1, acc2, acc3);
#pragma unroll
            for (int u = 0; u < 12; ++u)
                rank1(M[u], __shfl(a10, 12 + u, 64), __shfl(a11, 12 + u, 64),
                      __shfl(a12, 12 + u, 64), __shfl(a13, 12 + u, 64),
                      acc0, acc1, acc2, acc3);
#pragma unroll
            for (int u = 0; u < 12; ++u)
                rank1(T[u], __shfl(a10, 24 + u, 64), __shfl(a11, 24 + u, 64),
                      __shfl(a12, 24 + u, 64), __shfl(a13, 24 + u, 64),
                      acc0, acc1, acc2, acc3);
        }

        // ---- Phase C: slice partials (wa/wb prefetched last step; W3s zeros
        // beyond prefix L keep the full-slice dot exact)
        float s00 = 0, s01 = 0, s10 = 0, s11 = 0;
        float s20 = 0, s21 = 0, s30 = 0, s31 = 0;
        if (doC) {
            float hx, hy, hz, hw;
            hx = fmaxf(acc0.x, 0.0f); hy = fmaxf(acc0.y, 0.0f);
            hz = fmaxf(acc0.z, 0.0f); hw = fmaxf(acc0.w, 0.0f);
            s00 = fmaf(wa.x, hx, fmaf(wa.y, hy, fmaf(wa.z, hz, wa.w * hw)));
            s01 = fmaf(wb.x, hx, fmaf(wb.y, hy, fmaf(wb.z, hz, wb.w * hw)));
            hx = fmaxf(acc1.x, 0.0f); hy = fmaxf(acc1.y, 0.0f);
            hz = fmaxf(acc1.z, 0.0f); hw = fmaxf(acc1.w, 0.0f);
            s10 = fmaf(wa.x, hx, fmaf(wa.y, hy, fmaf(wa.z, hz, wa.w * hw)));
            s11 = fmaf(wb.x, hx, fmaf(wb.y, hy, fmaf(wb.z, hz, wb.w * hw)));
            hx = fmaxf(acc2.x, 0.0f); hy = fmaxf(acc2.y, 0.0f);
            hz = fmaxf(acc2.z, 0.0f); hw = fmaxf(acc2.w, 0.0f);
            s20 = fmaf(wa.x, hx, fmaf(wa.y, hy, fmaf(wa.z, hz, wa.w * hw)));
            s21 = fmaf(wb.x, hx, fmaf(wb.y, hy, fmaf(wb.z, hz, wb.w * hw)));
            hx = fmaxf(acc3.x, 0.0f); hy = fmaxf(acc3.y, 0.0f);
            hz = fmaxf(acc3.z, 0.0f); hw = fmaxf(acc3.w, 0.0f);
            s30 = fmaf(wa.x, hx, fmaf(wa.y, hy, fmaf(wa.z, hz, wa.w * hw)));
            s31 = fmaf(wb.x, hx, fmaf(wb.y, hy, fmaf(wb.z, hz, wb.w * hw)));
        }
#pragma unroll
        for (int m = 32; m >= 1; m >>= 1) {
            s00 += __shfl_xor(s00, m, 64); s01 += __shfl_xor(s01, m, 64);
            s10 += __shfl_xor(s10, m, 64); s11 += __shfl_xor(s11, m, 64);
            s20 += __shfl_xor(s20, m, 64); s21 += __shfl_xor(s21, m, 64);
            s30 += __shfl_xor(s30, m, 64); s31 += __shfl_xor(s31, m, 64);
        }
        if (lane == 0) {
            float* pp = &part[i & 1][w][0];
            ((float4*)pp)[0] = make_float4(s00, s01, s10, s11);
            ((float4*)pp)[1] = make_float4(s20, s21, s30, s31);
        }

        // ---- cross-barrier prefetch for step i+1 (latency hides under the
        // barrier + combine + transcendentals)
        const int in = i + 1;
        if (in < NI) {
            const int goff_n = (in <= 1) ? 0 : (33 * (in - 1) + 1);
            if (gb + 256 > goff_n) {
                const float* rbn = W2t + (size_t)goff_n * NH + gb;
#pragma unroll
                for (int u = 0; u < 12; ++u)
                    P[u] = ((const float4*)(rbn + (size_t)u * NH))[lane];
            }
            if (gb < 33 * in + 1) {
                wa = ((const float4*)(W3s + (size_t)in * NH + gb))[lane];
                wb = ((const float4*)(W3s + (size_t)(NI + in) * NH + gb))[lane];
            } else {
                wa = make_float4(0, 0, 0, 0);
                wb = make_float4(0, 0, 0, 0);
            }
        }
        __syncthreads();

        // ---- combine partials; rows packed into lanes (lane&3) -> one tanh/exp
        const float* pb = &part[i & 1][0][0];
        float4 Aq = make_float4(0, 0, 0, 0), Bq = make_float4(0, 0, 0, 0);
#pragma unroll
        for (int ww = 0; ww < 4; ++ww) {
            float4 ta = ((const float4*)pb)[2 * ww];
            float4 tb = ((const float4*)pb)[2 * ww + 1];
            Aq.x += ta.x; Aq.y += ta.y; Aq.z += ta.z; Aq.w += ta.w;
            Bq.x += tb.x; Bq.y += tb.y; Bq.z += tb.z; Bq.w += tb.w;
        }
        const int lr = lane & 3;
        float p0p = (lr == 0) ? Aq.x : (lr == 1) ? Aq.z : (lr == 2) ? Bq.x : Bq.z;
        float p1p = (lr == 0) ? Aq.y : (lr == 1) ? Aq.w : (lr == 2) ? Bq.y : Bq.w;
        p0p += __shfl(b3v, i, 64);
        p1p += __shfl(b3v, NI + i, 64);
        float xi0 = __shfl(xin0, i, 64), xi1 = __shfl(xin1, i, 64);
        float xi2 = __shfl(xin2, i, 64), xi3 = __shfl(xin3, i, 64);
        float xinp = (lr == 0) ? xi0 : (lr == 1) ? xi1 : (lr == 2) ? xi2 : xi3;
        float e2 = __expf(2.0f * fminf(p1p, 15.0f));   // tanh; exact sat both ends
        float ap = (e2 - 1.0f) / (e2 + 1.0f);
        float xp = fmaf(xinp, __expf(ap), p0p);
        float av0 = __shfl(ap, 0, 64), av1 = __shfl(ap, 1, 64);
        float av2 = __shfl(ap, 2, 64), av3 = __shfl(ap, 3, 64);
        float xv0 = __shfl(xp, 0, 64), xv1 = __shfl(xp, 1, 64);
        float xv2 = __shfl(xp, 2, 64), xv3 = __shfl(xp, 3, 64);
        J0 -= av0; J1 -= av1; J2 -= av2; J3 -= av3;
        if (lane == i) { xr0 = xv0; xr1 = xv1; xr2 = xv2; xr3 = xv3; }
    }

    if (w == 0) {
        if (lane < NI) {
            out[(row0 + 0) * NI + lane] = xr0;
            out[(row0 + 1) * NI + lane] = xr1;
            out[(row0 + 2) * NI + lane] = xr2;
            out[(row0 + 3) * NI + lane] = xr3;
        }
        if (lane < 4) {
            float Jv = (lane == 0) ? J0 : (lane == 1) ? J1 : (lane == 2) ? J2 : J3;
            out[B * NI + row0 + lane] = Jv;
        }
    }
}

extern "C" void kernel_launch(void* const* d_in, const int* in_sizes, int n_in,
                              void* d_out, int out_size, void* d_ws, size_t ws_size,
                              hipStream_t stream) {
    const float* inputs = (const float*)d_in[0];
    const float* W1     = (const float*)d_in[1];
    const float* b1     = (const float*)d_in[2];
    const float* W2     = (const float*)d_in[3];
    const float* b2     = (const float*)d_in[4];
    const float* W3     = (const float*)d_in[5];
    const float* b3     = (const float*)d_in[6];
    float* out = (float*)d_out;
    float* ws  = (float*)d_ws;

    prep_all<<<353, 256, 0, stream>>>(W1, b1, W2, b2, W3, ws);
    made_scan<<<B / 4, 256, 0, stream>>>(inputs, b3, ws, out);
}

// Round 8
// 189.842 us; speedup vs baseline: 1.3298x; 1.2197x over previous
//
#include <hip/hip_runtime.h>
#include <math.h>

#define NI   32
#define NH   1024
#define NB   1024

// ws layout (floats). g-axis (h2 units) degree-SORTED (suffix skip); h1-axis NATURAL.
//   W1t [32][1056] : W1t[j][s] = m1-masked W1[orig(s)][j], s sorted (stride-padded)
//   b1s [1056]     : sorted b1 (overread lanes masked)
//   b2s [1024]     : sorted b2
//   W3s [64][1024] : m3-masked, sorted columns
//   W2t [1054][1024]: W2t[oh][sg] = m2-masked W2[orig(sg)][oh]; rows natural oh,
//                     +30 pad rows for u-overrun loads (x0.0, 0xAA = finite)
#define W1T_STRIDE 1056
#define OFF_W1T 0
#define OFF_B1S (32 * W1T_STRIDE)          // 33792
#define OFF_B2S (OFF_B1S + W1T_STRIDE)     // 34848
#define OFF_W3S (OFF_B2S + NH)             // 35872
#define OFF_W2T (OFF_W3S + 64 * NH)        // 101408
// total = 101408 + 1054*1024 = 1180704 floats (~4.72 MB)

// degree class d: units h = d, d+31, ... ; d=0 has 34 units, d>=1 has 33.
__device__ __forceinline__ int base_of(int d) { return (d == 0) ? 0 : 34 + 33 * (d - 1); }

// ---- prep: per-degree-class transpose; writes are >=132B-contiguous runs ----
template <int CNT>
__device__ __forceinline__ void prep_w2_cls(int d, int oh0, const float* __restrict__ W2,
                                            float* __restrict__ ws, int t,
                                            float (*tile)[257]) {
    const int bse = base_of(d);
#pragma unroll 1
    for (int p = 0; p < (CNT + 3) / 4; ++p) {       // coalesced reads of W2 rows (og class)
        int k = p * 4 + (t >> 6);
        if (k < CNT) {
            int og = d + 31 * k;
            float4 v = ((const float4*)(W2 + (size_t)og * NH + oh0))[t & 63];
            int c = (t & 63) * 4;
            tile[k][c] = v.x; tile[k][c + 1] = v.y;
            tile[k][c + 2] = v.z; tile[k][c + 3] = v.w;
        }
    }
    __syncthreads();
#pragma unroll 1
    for (int it = 0; it < CNT; ++it) {              // writes: runs of CNT contiguous floats
        int e = it * 256 + t;
        int oh_l = e / CNT;                         // const divide -> magic mul
        int k = e - oh_l * CNT;
        int oh = oh0 + oh_l;
        float v = (d >= (oh % 31)) ? tile[k][oh_l] : 0.0f;
        ws[OFF_W2T + (size_t)oh * NH + bse + k] = v;
    }
}

template <int CNT>
__device__ __forceinline__ void prep_small_cls(int d, const float* __restrict__ W1,
        const float* __restrict__ b1, const float* __restrict__ b2,
        const float* __restrict__ W3, float* __restrict__ ws, int t) {
    const int bse = base_of(d);
#pragma unroll 1
    for (int e = t; e < 64 * CNT; e += 256) {       // W3s
        int o = e / CNT, k = e - o * CNT;
        int og = d + 31 * k;
        float v = (((o & 31) - 1) >= d) ? W3[(size_t)o * NH + og] : 0.0f;
        ws[OFF_W3S + (size_t)o * NH + bse + k] = v;
    }
#pragma unroll 1
    for (int e = t; e < 32 * CNT; e += 256) {       // W1t
        int j = e / CNT, k = e - j * CNT;
        int og = d + 31 * k;
        float v = (d >= j) ? W1[og * NI + j] : 0.0f;
        ws[OFF_W1T + j * W1T_STRIDE + bse + k] = v;
    }
    if (t < CNT) {                                  // biases
        int og = d + 31 * t;
        ws[OFF_B1S + bse + t] = b1[og];
        ws[OFF_B2S + bse + t] = b2[og];
    }
}

__global__ __launch_bounds__(256) void prep_all(const float* __restrict__ W1,
        const float* __restrict__ b1, const float* __restrict__ W2,
        const float* __restrict__ b2, const float* __restrict__ W3,
        float* __restrict__ ws) {
    __shared__ float tile[34][257];
    const int bid = blockIdx.x, t = threadIdx.x;
    if (bid < 124) {                                 // 31 classes x 4 oh-chunks
        int d = bid >> 2, oh0 = (bid & 3) * 256;
        if (d == 0) prep_w2_cls<34>(0, oh0, W2, ws, t, tile);
        else        prep_w2_cls<33>(d, oh0, W2, ws, t, tile);
    } else {                                         // 31 classes: W3s/W1t/biases
        int d = bid - 124;
        if (d == 0) prep_small_cls<34>(0, W1, b1, b2, W3, ws, t);
        else        prep_small_cls<33>(d, W1, b1, b2, W3, ws, t);
    }
}

__device__ __forceinline__ void fma4x2(float4& a0, float4& a1, float4 wv,
                                       float c0, float c1) {
    a0.x = fmaf(c0, wv.x, a0.x); a0.y = fmaf(c0, wv.y, a0.y);
    a0.z = fmaf(c0, wv.z, a0.z); a0.w = fmaf(c0, wv.w, a0.w);
    a1.x = fmaf(c1, wv.x, a1.x); a1.y = fmaf(c1, wv.y, a1.y);
    a1.z = fmaf(c1, wv.z, a1.z); a1.w = fmaf(c1, wv.w, a1.w);
}

// Block = 2 batch rows x 4 slice-waves (float4/lane). 512 blocks = 2/CU, all
// co-resident, 2 waves/SIMD. B's 34 panel loads forced into 3 wide in-flight
// groups with sched_barrier fences; phase A fixed-32-tap with hoisted loads.
__global__ __launch_bounds__(256, 2) void made_scan(
        const float* __restrict__ inputs,
        const float* __restrict__ b3,
        const float* __restrict__ ws,
        float* __restrict__ out) {
    __shared__ float part[2][4][4];     // [buf][wave][s00,s01,s10,s11]

    const int lane = threadIdx.x & 63;
    const int w    = threadIdx.x >> 6;
    const int gb   = w * 256;           // sorted-g slice base
    const int row0 = blockIdx.x * 2;

    const float* W1t = ws + OFF_W1T;
    const float* b1s = ws + OFF_B1S;
    const float* b2s = ws + OFF_B2S;
    const float* W3s = ws + OFF_W3S;
    const float* W2t = ws + OFF_W2T;

    float4 acc0 = ((const float4*)(b2s + gb))[lane];   // z2 slice, rows 0/1
    float4 acc1 = acc0;
    float xin0 = (lane < NI) ? inputs[row0 * NI + lane] : 0.0f;
    float xin1 = (lane < NI) ? inputs[(row0 + 1) * NI + lane] : 0.0f;
    float b3v  = b3[lane];
    float xr0 = 0.f, xr1 = 0.f, J0 = 0.f, J1 = 0.f;    // x_j in lane j

#pragma unroll 1
    for (int i = 0; i < NI; ++i) {
        const int dd   = i - 1;
        const int goff = (i <= 1) ? 0 : (33 * i - 32);  // base(i-1)
        const int cnt  = (i == 1) ? 34 : 33;
        const int L    = 33 * i + 1;                    // base(i), i>=1
        const bool doB = (i > 0) && (gb + 256 > goff);
        const bool doC = (i > 0) && (gb < L);

        float4 wa = make_float4(0, 0, 0, 0), wb = make_float4(0, 0, 0, 0);
        if (doC) {                                      // C weights: issue early
            wa = ((const float4*)(W3s + (size_t)i * NH + gb))[lane];
            wb = ((const float4*)(W3s + (size_t)(NI + i) * NH + gb))[lane];
        }

        if (doB) {
            const int su = goff + lane;                 // sorted unit idx for lane
            float bz = b1s[su];
            float w1v[32];
#pragma unroll
            for (int j = 0; j < 32; ++j) w1v[j] = W1t[j * W1T_STRIDE + su];

            const float* rb = W2t + (size_t)dd * NH + gb;   // row oh = dd + 31u
            float4 g1[12];
#pragma unroll
            for (int u = 0; u < 12; ++u)
                g1[u] = ((const float4*)(rb + (size_t)u * 31 * NH))[lane];
            __builtin_amdgcn_sched_barrier(0);

            // ---- Phase A (2 rows): fixed 32 taps; j>=i taps are exact zeros
            float zA0 = bz, zA1 = 0, zA2 = 0, zA3 = 0;
            float zB0 = bz, zB1 = 0, zB2 = 0, zB3 = 0;
#pragma unroll
            for (int j = 0; j < 32; j += 4) {
                zA0 = fmaf(__shfl(xr0, j + 0, 64), w1v[j + 0], zA0);
                zB0 = fmaf(__shfl(xr1, j + 0, 64), w1v[j + 0], zB0);
                zA1 = fmaf(__shfl(xr0, j + 1, 64), w1v[j + 1], zA1);
                zB1 = fmaf(__shfl(xr1, j + 1, 64), w1v[j + 1], zB1);
                zA2 = fmaf(__shfl(xr0, j + 2, 64), w1v[j + 2], zA2);
                zB2 = fmaf(__shfl(xr1, j + 2, 64), w1v[j + 2], zB2);
                zA3 = fmaf(__shfl(xr0, j + 3, 64), w1v[j + 3], zA3);
                zB3 = fmaf(__shfl(xr1, j + 3, 64), w1v[j + 3], zB3);
            }
            const bool ok = lane < cnt;
            float a0 = ok ? fmaxf((zA0 + zA1) + (zA2 + zA3), 0.f) : 0.f;
            float a1 = ok ? fmaxf((zB0 + zB1) + (zB2 + zB3), 0.f) : 0.f;
            __builtin_amdgcn_sched_barrier(0);

            float4 g2[12];
#pragma unroll
            for (int u = 0; u < 12; ++u)
                g2[u] = ((const float4*)(rb + (size_t)(12 + u) * 31 * NH))[lane];
            __builtin_amdgcn_sched_barrier(0);
#pragma unroll
            for (int u = 0; u < 12; ++u)
                fma4x2(acc0, acc1, g1[u], __shfl(a0, u, 64), __shfl(a1, u, 64));
            __builtin_amdgcn_sched_barrier(0);

            float4 g3[10];
#pragma unroll
            for (int u = 0; u < 10; ++u)
                g3[u] = ((const float4*)(rb + (size_t)(24 + u) * 31 * NH))[lane];
            __builtin_amdgcn_sched_barrier(0);
#pragma unroll
            for (int u = 0; u < 12; ++u)
                fma4x2(acc0, acc1, g2[u], __shfl(a0, 12 + u, 64), __shfl(a1, 12 + u, 64));
            __builtin_amdgcn_sched_barrier(0);
#pragma unroll
            for (int u = 0; u < 10; ++u)
                fma4x2(acc0, acc1, g3[u], __shfl(a0, 24 + u, 64), __shfl(a1, 24 + u, 64));
        }

        // ---- Phase C: slice partials (W3s zeros beyond prefix keep it exact)
        float s00 = 0, s01 = 0, s10 = 0, s11 = 0;
        if (doC) {
            float hx, hy, hz, hw;
            hx = fmaxf(acc0.x, 0.f); hy = fmaxf(acc0.y, 0.f);
            hz = fmaxf(acc0.z, 0.f); hw = fmaxf(acc0.w, 0.f);
            s00 = fmaf(wa.x, hx, fmaf(wa.y, hy, fmaf(wa.z, hz, wa.w * hw)));
            s01 = fmaf(wb.x, hx, fmaf(wb.y, hy, fmaf(wb.z, hz, wb.w * hw)));
            hx = fmaxf(acc1.x, 0.f); hy = fmaxf(acc1.y, 0.f);
            hz = fmaxf(acc1.z, 0.f); hw = fmaxf(acc1.w, 0.f);
            s10 = fmaf(wa.x, hx, fmaf(wa.y, hy, fmaf(wa.z, hz, wa.w * hw)));
            s11 = fmaf(wb.x, hx, fmaf(wb.y, hy, fmaf(wb.z, hz, wb.w * hw)));
#pragma unroll
            for (int m = 32; m >= 1; m >>= 1) {
                s00 += __shfl_xor(s00, m, 64); s01 += __shfl_xor(s01, m, 64);
                s10 += __shfl_xor(s10, m, 64); s11 += __shfl_xor(s11, m, 64);
            }
        }
        if (lane == 0)
            *((float4*)&part[i & 1][w][0]) = make_float4(s00, s01, s10, s11);
        __syncthreads();

        // ---- combine (replicated in all lanes/waves -> identical xr update)
        const float* pb = &part[i & 1][0][0];
        float4 q0 = ((const float4*)pb)[0], q1 = ((const float4*)pb)[1];
        float4 q2 = ((const float4*)pb)[2], q3 = ((const float4*)pb)[3];
        float bi  = __shfl(b3v, i, 64);
        float bia = __shfl(b3v, NI + i, 64);
        float p00 = ((q0.x + q1.x) + (q2.x + q3.x)) + bi;
        float p01 = ((q0.y + q1.y) + (q2.y + q3.y)) + bia;
        float p10 = ((q0.z + q1.z) + (q2.z + q3.z)) + bi;
        float p11 = ((q0.w + q1.w) + (q2.w + q3.w)) + bia;
        float e20 = __expf(2.f * fminf(p01, 15.f));
        float ta0 = (e20 - 1.f) / (e20 + 1.f);
        float x0  = fmaf(__shfl(xin0, i, 64), __expf(ta0), p00);
        float e21 = __expf(2.f * fminf(p11, 15.f));
        float ta1 = (e21 - 1.f) / (e21 + 1.f);
        float x1  = fmaf(__shfl(xin1, i, 64), __expf(ta1), p10);
        J0 -= ta0; J1 -= ta1;
        if (lane == i) { xr0 = x0; xr1 = x1; }
    }

    if (w == 0) {
        if (lane < NI) {
            out[row0 * NI + lane]       = xr0;
            out[(row0 + 1) * NI + lane] = xr1;
        }
        if (lane == 0) {
            out[NB * NI + row0]     = J0;
            out[NB * NI + row0 + 1] = J1;
        }
    }
}

extern "C" void kernel_launch(void* const* d_in, const int* in_sizes, int n_in,
                              void* d_out, int out_size, void* d_ws, size_t ws_size,
                              hipStream_t stream) {
    const float* inputs = (const float*)d_in[0];
    const float* W1     = (const float*)d_in[1];
    const float* b1     = (const float*)d_in[2];
    const float* W2     = (const float*)d_in[3];
    const float* b2     = (const float*)d_in[4];
    const float* W3     = (const float*)d_in[5];
    const float* b3     = (const float*)d_in[6];
    float* out = (float*)d_out;
    float* ws  = (float*)d_ws;

    prep_all<<<155, 256, 0, stream>>>(W1, b1, W2, b2, W3, ws);
    made_scan<<<NB / 2, 256, 0, stream>>>(inputs, b3, ws, out);
}